// Round 15
// baseline (148.310 us; speedup 1.0000x reference)
//
#include <hip/hip_runtime.h>
#include <hip/hip_bf16.h>

#define N_NODES 20000
#define N_EDGES 320000
#define IN_DIM  1024
#define H_HEADS 8
#define C_CH    64
#define HC      512
#define LEAKY   0.2f
#define LN_EPS  1e-5f

// Extended (transposed) weight: rows 0..511 = W_src cols, 512..519 = att_src fold,
// 520..527 = att_dst fold, 528..575 zero pad.  wbT[col][k], bf16.
#define BCOLS 576

typedef short bf16x8 __attribute__((ext_vector_type(8)));
typedef float f32x4  __attribute__((ext_vector_type(4)));

__device__ __forceinline__ unsigned short f2bf(float f) {
    union { float f; unsigned int u; } c; c.f = f;
    unsigned int u = c.u;
    unsigned int r = (u + 0x7fffu + ((u >> 16) & 1u)) >> 16;   // RNE
    return (unsigned short)r;
}
__device__ __forceinline__ float bf2f(unsigned int h) {
    union { unsigned int u; float f; } c; c.u = h << 16; return c.f;
}
// HW packed f32->bf16 (RNE), 1 instr per 2 elements (gfx950; m214v22)
__device__ __forceinline__ unsigned int cvtpk(float lo, float hi) {
    unsigned int r;
    asm("v_cvt_pk_bf16_f32 %0, %1, %2" : "=v"(r) : "v"(lo), "v"(hi));
    return r;
}
__device__ __forceinline__ void gload_lds16(const void* g, void* l) {
    __builtin_amdgcn_global_load_lds(
        (const __attribute__((address_space(1))) unsigned int*)g,
        (__attribute__((address_space(3))) unsigned int*)l, 16, 0, 0);
}

// ---------------------------------------------------------------------------
#define DEG_BLOCKS 1250

__global__ __launch_bounds__(256) void deg_hist(
        const int* __restrict__ ei, int* __restrict__ deg) {
    int e = blockIdx.x * 256 + threadIdx.x;           // 1250*256 == N_EDGES
    atomicAdd(&deg[ei[N_EDGES + e]], 1);
}

// ---------------------------------------------------------------------------
// Build wbT (bf16, [BCOLS][IN_DIM]).  grid = 1024 prep blocks + 1 scan tail
// block.  Scan is vectorized: 125 threads x 160 elements (40 x int4).
__global__ void prep_w_scan(const float* __restrict__ Wsrc,
                            const float* __restrict__ Wdst,
                            const float* __restrict__ att_src,
                            const float* __restrict__ att_dst,
                            short* __restrict__ wbT,
                            const int* __restrict__ deg,
                            int* __restrict__ off,
                            int* __restrict__ cursor) {
    int t = threadIdx.x;                  // block = 128 threads

    if (blockIdx.x == IN_DIM) {           // ---- scan tail block
        __shared__ int wtot[2];
        int lane = t & 63, w = t >> 6;
        const int4* deg4 = (const int4*)deg;
        int s = 0;
        if (t < 125) {                    // 125*160 == N_NODES exactly
            #pragma unroll
            for (int j = 0; j < 40; ++j) {
                int4 u = deg4[t * 40 + j];
                s += u.x + u.y + u.z + u.w;
            }
        }
        int v = s;
        #pragma unroll
        for (int o = 1; o < 64; o <<= 1) {
            int u = __shfl_up(v, o);
            if (lane >= o) v += u;
        }
        if (lane == 63) wtot[w] = v;
        __syncthreads();
        int add = (w == 1) ? wtot[0] : 0;
        int run = add + v - s;            // exclusive prefix of this segment
        if (t < 125) {
            int4* off4 = (int4*)off;
            int4* cur4 = (int4*)cursor;
            #pragma unroll
            for (int j = 0; j < 40; ++j) {
                int4 u = deg4[t * 40 + j];
                int4 o_;
                o_.x = run;
                o_.y = o_.x + u.x;
                o_.z = o_.y + u.y;
                o_.w = o_.z + u.z;
                off4[t * 40 + j] = o_;
                cur4[t * 40 + j] = o_;
                run = o_.w + u.w;
            }
            if (t == 124) off[N_NODES] = run;
        }
        return;
    }

    int k = blockIdx.x;
    float4 v = *(const float4*)(Wsrc + (size_t)k * HC + t * 4);
    wbT[(size_t)(t * 4 + 0) * IN_DIM + k] = (short)f2bf(v.x);
    wbT[(size_t)(t * 4 + 1) * IN_DIM + k] = (short)f2bf(v.y);
    wbT[(size_t)(t * 4 + 2) * IN_DIM + k] = (short)f2bf(v.z);
    wbT[(size_t)(t * 4 + 3) * IN_DIM + k] = (short)f2bf(v.w);
    if (t < 16) {
        int h = t & 7;
        const float* W   = (t < 8) ? Wsrc : Wdst;
        const float* att = (t < 8) ? att_src : att_dst;
        float s = 0.f;
        #pragma unroll
        for (int c = 0; c < C_CH; ++c)
            s += W[(size_t)k * HC + h * C_CH + c] * att[h * C_CH + c];
        wbT[(size_t)(512 + t) * IN_DIM + k] = (short)f2bf(s);
    } else if (t < 64) {
        wbT[(size_t)(512 + t) * IN_DIM + k] = 0;   // pad cols 528..575
    }
}

// ---------------------------------------------------------------------------
// MFMA GEMM (BM=64 x BN=96 x BK=64, 4 waves 2x2, 1878 blocks) with a TRUE
// counted-vmcnt pipeline (T4): per step s,
//   issue A(s+2) reg-loads + B(s+1) gload_lds   (top of step)
//   s_waitcnt vmcnt(7)    <- waits ONLY B(s), issued a FULL STEP earlier
//   barrier; COMPUTE(s); A_WRITE(s+1) (A regs had step+compute cover);
//   lgkmcnt(0); barrier.
// Never drains vmcnt to 0 until the peeled tail (vmcnt(3)/vmcnt(0)).
// A regs double-buffered (static idx via full unroll).  LDS 40 KB (=R14),
// 4 blocks/CU.  Swizzled layout unchanged (0 bank conflicts measured).
// Blocks [0,NWG): GEMM.  Blocks [NWG,NWG+DEG_BLOCKS): CSR edge scatter.
#define BM 64
#define BN 96
#define BK 64
#define NCOLT (BCOLS / BN)                  // 6
#define NROWT ((N_NODES + BM - 1) / BM)     // 313
#define NWG (NCOLT * NROWT)                 // 1878
#define KSTEPS (IN_DIM / BK)                // 16
#define A_SLOTS (BM * BK / 8)               // 512 x 16B = 8 KB
#define B_SLOTS (BN * BK / 8)               // 768 x 16B = 12 KB

#define WAITV(n) asm volatile("s_waitcnt vmcnt(" #n ")" ::: "memory")

__global__ __launch_bounds__(256) void gemm_scatter(
        const float* __restrict__ x,
        const short* __restrict__ wbT,
        short* __restrict__ xsb,
        float* __restrict__ a_srcv,
        float* __restrict__ a_dstv,
        const int* __restrict__ ei,
        int* __restrict__ cursor,
        int* __restrict__ csr_src) {
    __shared__ short As[2][A_SLOTS * 8];    // 2 x 8 KB
    __shared__ short Bs[2][B_SLOTS * 8];    // 2 x 12 KB  (40 KB total)

    int t = threadIdx.x;

    // ---- scatter blocks: bare CSR scatter, sorted by dst
    if (blockIdx.x >= NWG) {
        int e = (blockIdx.x - NWG) * 256 + t;   // 1250*256 == N_EDGES exactly
        int d = ei[N_EDGES + e];
        int idx = atomicAdd(&cursor[d], 1);
        csr_src[idx] = ei[e];
        return;
    }

    // bijective XCD swizzle (m204): contiguous chunk of wgids per XCD
    int orig = blockIdx.x;
    const int q = NWG >> 3, r = NWG & 7;
    int xcd  = orig & 7;
    int wgid = (xcd < r ? xcd * (q + 1) : r * (q + 1) + (xcd - r) * q) + (orig >> 3);
    int col0 = (wgid % NCOLT) * BN;         // col tiles fastest -> A rows L2-local
    int row0 = (wgid / NCOLT) * BM;

    int lane = t & 63;
    int w    = t >> 6;
    int lr   = lane & 15;
    int lg   = lane >> 4;                   // k-group 0..3
    int sw   = lr & 7;                      // fragment-read swizzle key
    int wr   = (w >> 1) * 32;               // wave row offset (2x2 waves)
    int wc   = (w & 1) * 48;                // wave col offset

    // A staging source (fp32): slot s: m = s>>3, kcp = s&7; chunk kc = kcp^(m&7)
    const float* a_base[2];
    #pragma unroll
    for (int i = 0; i < 2; ++i) {
        int s  = t + 256 * i;               // 0..511
        int m  = s >> 3;
        int kc = (s & 7) ^ (m & 7);
        int gm = row0 + m;
        if (gm >= N_NODES) gm = N_NODES - 1;   // clamp (dead rows, in-bounds)
        a_base[i] = x + (size_t)gm * IN_DIM + kc * 8;
    }
    const short* b_base[3];
    #pragma unroll
    for (int i = 0; i < 3; ++i) {
        int s  = t + 256 * i;               // 0..767
        int c  = s >> 3;
        int kc = (s & 7) ^ (c & 7);
        b_base[i] = wbT + (size_t)(col0 + c) * IN_DIM + kc * 8;
    }

    f32x4 acc[2][3] = {};

#define A_WRITE(buf, fa0, fb0, fa1, fb1)                                      \
    do {                                                                      \
        uint4 r0, r1;                                                         \
        r0.x = cvtpk(fa0.x, fa0.y);  r0.y = cvtpk(fa0.z, fa0.w);              \
        r0.z = cvtpk(fb0.x, fb0.y);  r0.w = cvtpk(fb0.z, fb0.w);              \
        r1.x = cvtpk(fa1.x, fa1.y);  r1.y = cvtpk(fa1.z, fa1.w);              \
        r1.z = cvtpk(fb1.x, fb1.y);  r1.w = cvtpk(fb1.z, fb1.w);              \
        *(uint4*)(&As[buf][(t      ) * 8]) = r0;                              \
        *(uint4*)(&As[buf][(t + 256) * 8]) = r1;                              \
    } while (0)

#define COMPUTE(buf)                                                          \
    do {                                                                      \
        _Pragma("unroll")                                                     \
        for (int ks = 0; ks < 2; ++ks) {                                      \
            int kc  = ks * 4 + lg;                                            \
            int kca = kc ^ sw;                                                \
            bf16x8 af[2], bfr[3];                                             \
            _Pragma("unroll")                                                 \
            for (int mi = 0; mi < 2; ++mi)                                    \
                af[mi] = *(const bf16x8*)(&As[buf][((wr + mi * 16 + lr) * 8 + kca) * 8]); \
            _Pragma("unroll")                                                 \
            for (int ni = 0; ni < 3; ++ni)                                    \
                bfr[ni] = *(const bf16x8*)(&Bs[buf][((wc + ni * 16 + lr) * 8 + kca) * 8]); \
            __builtin_amdgcn_s_setprio(1);                                    \
            _Pragma("unroll")                                                 \
            for (int mi = 0; mi < 2; ++mi)                                    \
                _Pragma("unroll")                                             \
                for (int ni = 0; ni < 3; ++ni)                                \
                    acc[mi][ni] = __builtin_amdgcn_mfma_f32_16x16x32_bf16(    \
                        af[mi], bfr[ni], acc[mi][ni], 0, 0, 0);               \
            __builtin_amdgcn_s_setprio(0);                                    \
        }                                                                     \
    } while (0)

    float4 AR[2][4];   // A-reg double buffer; indices static after full unroll

    // ---- prologue: A(0) temps, A(1) into AR[1], B(0) DMA; write As[0].
    // Issue order A(0), A(1), B(0) => B(0) is the newest; step-0 wait of
    // vmcnt(7) (A(2):4 + B(1):3 newer) drains exactly through B(0).
    {
        float4 p0 = *(const float4*)(a_base[0]);
        float4 p1 = *(const float4*)(a_base[0] + 4);
        float4 p2 = *(const float4*)(a_base[1]);
        float4 p3 = *(const float4*)(a_base[1] + 4);
        AR[1][0] = *(const float4*)(a_base[0] + BK);
        AR[1][1] = *(const float4*)(a_base[0] + BK + 4);
        AR[1][2] = *(const float4*)(a_base[1] + BK);
        AR[1][3] = *(const float4*)(a_base[1] + BK + 4);
        #pragma unroll
        for (int i = 0; i < 3; ++i)
            gload_lds16(b_base[i], &Bs[0][(t + 256 * i) * 8]);
        A_WRITE(0, p0, p1, p2, p3);     // compiler waits A(0) (vmcnt auto)
        asm volatile("s_waitcnt lgkmcnt(0)" ::: "memory");
    }

    #pragma unroll
    for (int s = 0; s < KSTEPS; ++s) {
        // top of step: issue A(s+2) regs and B(s+1) DMA (full-step cover)
        if (s + 2 < KSTEPS) {
            int k2 = (s + 2) * BK;
            AR[s & 1][0] = *(const float4*)(a_base[0] + k2);
            AR[s & 1][1] = *(const float4*)(a_base[0] + k2 + 4);
            AR[s & 1][2] = *(const float4*)(a_base[1] + k2);
            AR[s & 1][3] = *(const float4*)(a_base[1] + k2 + 4);
        }
        if (s + 1 < KSTEPS) {
            int k1 = (s + 1) * BK;
            #pragma unroll
            for (int i = 0; i < 3; ++i)
                gload_lds16(b_base[i] + k1, &Bs[(s + 1) & 1][(t + 256 * i) * 8]);
        }
        // wait ONLY for B(s): steady state leaves A(s+2):4 + B(s+1):3 in flight
        if (s + 2 < KSTEPS)      WAITV(7);
        else if (s + 1 < KSTEPS) WAITV(3);
        else                     WAITV(0);
        __builtin_amdgcn_s_barrier();       // all waves' B(s) + As[s] visible

        COMPUTE(s & 1);

        if (s + 1 < KSTEPS)
            A_WRITE((s + 1) & 1, AR[(s + 1) & 1][0], AR[(s + 1) & 1][1],
                                 AR[(s + 1) & 1][2], AR[(s + 1) & 1][3]);
        asm volatile("s_waitcnt lgkmcnt(0)" ::: "memory");
        __builtin_amdgcn_s_barrier();       // As[s+1] visible; cur reads done
    }
#undef A_WRITE
#undef COMPUTE

    // epilogue: C/D layout col=lane&15, row=(lane>>4)*4+reg
    #pragma unroll
    for (int mi = 0; mi < 2; ++mi) {
        #pragma unroll
        for (int rr = 0; rr < 4; ++rr) {
            int row = row0 + wr + mi * 16 + lg * 4 + rr;
            if (row >= N_NODES) continue;
            #pragma unroll
            for (int ni = 0; ni < 3; ++ni) {
                int col = col0 + wc + ni * 16 + lr;
                float v = acc[mi][ni][rr];
                if (col < 512)      xsb[(size_t)row * HC + col] = (short)f2bf(v);
                else if (col < 520) a_srcv[(size_t)row * 8 + (col - 512)] = v;
                else if (col < 528) a_dstv[(size_t)row * 8 + (col - 520)] = v;
            }
        }
    }
}

// ---------------------------------------------------------------------------
// ONE WAVE per destination node (4 independent waves/block, no barriers).
// Lane owns 8 channels of one head: per edge, one dwordx4 gather per lane,
// one weight compute, 8 FMAs.  LN via 6-step shfl_xor across the wave.
__global__ __launch_bounds__(256) void aggregate_ln(
        const int* __restrict__ off,
        const int* __restrict__ csr_src,
        const float* __restrict__ a_srcv,
        const float* __restrict__ a_dstv,
        const short* __restrict__ xsb,
        const float* __restrict__ bias,
        const float* __restrict__ gamma,
        const float* __restrict__ beta,
        const float* __restrict__ prelu_a,
        float* __restrict__ out) {
    int lane = threadIdx.x & 63;
    int n    = blockIdx.x * 4 + (threadIdx.x >> 6);   // grid 5000 x 4 waves = 20000
    int ch0  = lane * 8;
    int h    = lane >> 3;

    int start = off[n], end = off[n + 1];
    float ad  = a_dstv[(size_t)n * 8 + h];

    float acc[8] = {};
    float wsum = 0.f;

    int i = start;
    for (; i + 1 < end; i += 2) {
        int s0 = __builtin_amdgcn_readfirstlane(csr_src[i]);
        int s1 = __builtin_amdgcn_readfirstlane(csr_src[i + 1]);
        float sc0 = a_srcv[(size_t)s0 * 8 + h] + ad;
        float sc1 = a_srcv[(size_t)s1 * 8 + h] + ad;
        uint4 u0 = *(const uint4*)(xsb + (size_t)s0 * HC + ch0);
        uint4 u1 = *(const uint4*)(xsb + (size_t)s1 * HC + ch0);
        sc0 = (sc0 >= 0.f) ? sc0 : LEAKY * sc0;
        sc1 = (sc1 >= 0.f) ? sc1 : LEAKY * sc1;
        float w0 = __expf(sc0);
        float w1 = __expf(sc1);
        acc[0] = fmaf(w0, bf2f(u0.x & 0xffffu), acc[0]);
        acc[1] = fmaf(w0, bf2f(u0.x >> 16),     acc[1]);
        acc[2] = fmaf(w0, bf2f(u0.y & 0xffffu), acc[2]);
        acc[3] = fmaf(w0, bf2f(u0.y >> 16),     acc[3]);
        acc[4] = fmaf(w0, bf2f(u0.z & 0xffffu), acc[4]);
        acc[5] = fmaf(w0, bf2f(u0.z >> 16),     acc[5]);
        acc[6] = fmaf(w0, bf2f(u0.w & 0xffffu), acc[6]);
        acc[7] = fmaf(w0, bf2f(u0.w >> 16),     acc[7]);
        acc[0] = fmaf(w1, bf2f(u1.x & 0xffffu), acc[0]);
        acc[1] = fmaf(w1, bf2f(u1.x >> 16),     acc[1]);
        acc[2] = fmaf(w1, bf2f(u1.y & 0xffffu), acc[2]);
        acc[3] = fmaf(w1, bf2f(u1.y >> 16),     acc[3]);
        acc[4] = fmaf(w1, bf2f(u1.z & 0xffffu), acc[4]);
        acc[5] = fmaf(w1, bf2f(u1.z >> 16),     acc[5]);
        acc[6] = fmaf(w1, bf2f(u1.w & 0xffffu), acc[6]);
        acc[7] = fmaf(w1, bf2f(u1.w >> 16),     acc[7]);
        wsum += w0 + w1;
    }
    if (i < end) {
        int s0 = __builtin_amdgcn_readfirstlane(csr_src[i]);
        float sc0 = a_srcv[(size_t)s0 * 8 + h] + ad;
        uint4 u0 = *(const uint4*)(xsb + (size_t)s0 * HC + ch0);
        sc0 = (sc0 >= 0.f) ? sc0 : LEAKY * sc0;
        float w0 = __expf(sc0);
        acc[0] = fmaf(w0, bf2f(u0.x & 0xffffu), acc[0]);
        acc[1] = fmaf(w0, bf2f(u0.x >> 16),     acc[1]);
        acc[2] = fmaf(w0, bf2f(u0.y & 0xffffu), acc[2]);
        acc[3] = fmaf(w0, bf2f(u0.y >> 16),     acc[3]);
        acc[4] = fmaf(w0, bf2f(u0.z & 0xffffu), acc[4]);
        acc[5] = fmaf(w0, bf2f(u0.z >> 16),     acc[5]);
        acc[6] = fmaf(w0, bf2f(u0.w & 0xffffu), acc[6]);
        acc[7] = fmaf(w0, bf2f(u0.w >> 16),     acc[7]);
        wsum += w0;
    }

    float inv = 1.f / (wsum + 1e-16f);
    float4 b0 = *(const float4*)(bias + ch0);
    float4 b1 = *(const float4*)(bias + ch0 + 4);
    float v8[8];
    float psum = 0.f, psq = 0.f;
    const float bb[8] = {b0.x, b0.y, b0.z, b0.w, b1.x, b1.y, b1.z, b1.w};
    #pragma unroll
    for (int j = 0; j < 8; ++j) {
        v8[j] = acc[j] * inv + bb[j];
        psum += v8[j];
        psq  += v8[j] * v8[j];
    }
    #pragma unroll
    for (int o = 32; o > 0; o >>= 1) {
        psum += __shfl_xor(psum, o);
        psq  += __shfl_xor(psq, o);
    }
    float mu   = psum * (1.f / (float)HC);
    float var  = psq * (1.f / (float)HC) - mu * mu;
    float rstd = rsqrtf(var + LN_EPS);

    float4 g0 = *(const float4*)(gamma + ch0);
    float4 g1 = *(const float4*)(gamma + ch0 + 4);
    float4 e0 = *(const float4*)(beta + ch0);
    float4 e1 = *(const float4*)(beta + ch0 + 4);
    float4 p0 = *(const float4*)(prelu_a + ch0);
    float4 p1 = *(const float4*)(prelu_a + ch0 + 4);
    const float gg[8] = {g0.x, g0.y, g0.z, g0.w, g1.x, g1.y, g1.z, g1.w};
    const float ee[8] = {e0.x, e0.y, e0.z, e0.w, e1.x, e1.y, e1.z, e1.w};
    const float pp[8] = {p0.x, p0.y, p0.z, p0.w, p1.x, p1.y, p1.z, p1.w};
    float y[8];
    #pragma unroll
    for (int j = 0; j < 8; ++j) {
        float v = (v8[j] - mu) * rstd * gg[j] + ee[j];
        y[j] = (v >= 0.f) ? v : pp[j] * v;
    }
    float4* o4 = (float4*)(out + (size_t)n * HC + ch0);
    o4[0] = make_float4(y[0], y[1], y[2], y[3]);
    o4[1] = make_float4(y[4], y[5], y[6], y[7]);
}

// ---------------------------------------------------------------------------
extern "C" void kernel_launch(void* const* d_in, const int* in_sizes, int n_in,
                              void* d_out, int out_size, void* d_ws, size_t ws_size,
                              hipStream_t stream) {
    const float* x        = (const float*)d_in[0];
    const int*   ei       = (const int*)d_in[2];
    const float* Wsrc     = (const float*)d_in[4];
    const float* Wdst     = (const float*)d_in[5];
    const float* att_src  = (const float*)d_in[6];
    const float* att_dst  = (const float*)d_in[7];
    const float* bias     = (const float*)d_in[8];
    const float* gamma    = (const float*)d_in[9];
    const float* beta     = (const float*)d_in[10];
    const float* prelu_a  = (const float*)d_in[11];
    float* out            = (float*)d_out;

    char*  ws = (char*)d_ws;
    size_t o  = 0;
    auto alloc = [&](size_t bytes) -> void* {
        void* p = ws + o;
        o += (bytes + 255) & ~(size_t)255;
        return p;
    };
    short* wbT     = (short*)alloc(sizeof(short) * BCOLS * IN_DIM);        // 1.18 MB
    short* xsb     = (short*)alloc(sizeof(short) * (size_t)N_NODES * HC);  // 20.5 MB
    float* a_srcv  = (float*)alloc(sizeof(float) * N_NODES * 8);
    float* a_dstv  = (float*)alloc(sizeof(float) * N_NODES * 8);
    int*   deg     = (int*)alloc(sizeof(int) * N_NODES);
    int*   off     = (int*)alloc(sizeof(int) * (N_NODES + 1));
    int*   cursor  = (int*)alloc(sizeof(int) * N_NODES);
    int*   csr_src = (int*)alloc(sizeof(int) * N_EDGES);                   // 1.28 MB

    hipMemsetAsync(deg, 0, sizeof(int) * N_NODES, stream);

    deg_hist<<<DEG_BLOCKS, 256, 0, stream>>>(ei, deg);

    // 1024 prep blocks + 1 scan tail block (scan needs deg from deg_hist)
    prep_w_scan<<<IN_DIM + 1, 128, 0, stream>>>(Wsrc, Wdst, att_src, att_dst,
                                                wbT, deg, off, cursor);

    // GEMM blocks (reading fp32 x directly) + fused edge_scatter blocks
    gemm_scatter<<<NWG + DEG_BLOCKS, 256, 0, stream>>>(
        x, wbT, xsb, a_srcv, a_dstv, ei, cursor, csr_src);

    aggregate_ln<<<N_NODES / 4, 256, 0, stream>>>(
        off, csr_src, a_srcv, a_dstv, xsb, bias, gamma, beta, prelu_a, out);
}